// Round 6
// baseline (703.403 us; speedup 1.0000x reference)
//
#include <hip/hip_runtime.h>
#include <hip/hip_cooperative_groups.h>
#include <float.h>
#include <math.h>

namespace cg = cooperative_groups;

// NNConv net: 2x edge-conditioned conv (scalar edge attr) + 2 FC + log_softmax.
// W_e = a_e*U_s + V_s over <=26 breakpoint segments of the scalar edge attr.
// R7: tail rebatched 4 nodes/wave via loop-order reuse -> 198 us, 9 launches.
// R8: full fusion into one cooperative kernel; FAILED with absmax 5.75 ==
// max|ref| -> output all zeros -> 512-block cooperative launch never ran
// (no occupancy clamp, no error check).
// R9: (1) grid clamped to hipOccupancyMaxActiveBlocksPerMultiprocessor x CUs,
// (2) launch error -> fall back to the proven R7 multi-kernel path,
// (3) explicit __threadfence() around grid.sync() for cross-XCD visibility.

#define NCONST 25
#define CH1 32   // edges per wave chunk, conv1
#define CH2 16   // edges per wave chunk, conv2
#define PACK_MASK 0x1FFFF  // edge id < 2^17 (E = 100000)
#define NBLK_MAX 512
#define NTHR 256

__device__ __forceinline__ void atomicMaxFloat(float* addr, float val) {
    if (val >= 0.f) atomicMax((int*)addr, __float_as_int(val));
    else            atomicMin((unsigned int*)addr, __float_as_uint(val));
}
__device__ __forceinline__ float readlane_f(float v, int l) {
    return __int_as_float(__builtin_amdgcn_readlane(__float_as_int(v), l));
}
__device__ __forceinline__ float elu_f(float a) {
    return a > 0.f ? a : expm1f(a);
}

struct MegaParams {
    const float *x; const int *src; const int *tgt; const float *ea;
    const float *w1a, *b1a, *w1b, *b1b, *wr1, *bias1;
    const float *w2a, *b2a, *w2b, *b2b, *wr2, *bias2;
    const float *fc1w, *fc1b, *fc2w, *fc2b;
    float *out;
    int *hist, *cur, *segp, *ord1, *ord2;   // ord1/ord2 contiguous
    float *U1, *V1, *U2, *V2, *AGG1, *AGG2, *H1b;  // AGG1/AGG2 contiguous
    int N, E, cap1, cap2;
};

__device__ __forceinline__ void gsync(cg::grid_group& grid) {
    __threadfence();   // release: publish non-atomic stores across XCD L2s
    grid.sync();
    __threadfence();   // acquire: drop stale lines before next phase reads
}

__global__ void __launch_bounds__(NTHR) mega_kernel(MegaParams p) {
    cg::grid_group grid = cg::this_grid();

    __shared__ float t1[NCONST], t2[NCONST];          // assign
    __shared__ int lh[64], lb[64];                    // assign/scatter
    __shared__ float swa[NCONST], sba[NCONST], stt[NCONST];  // build_uv
    __shared__ int srk[NCONST];
    __shared__ unsigned msk_sh;
    __shared__ __align__(16) float h1sh[4][4][32];    // tail
    __shared__ __align__(16) float h2sh[4][4][64];
    __shared__ __align__(16) float h3sh[4][4][132];
    __shared__ __align__(16) float wTsh[10][132];

    const int tid  = threadIdx.x;
    const int gtid = blockIdx.x * NTHR + tid;
    const int gsz  = gridDim.x * NTHR;
    const int lane = tid & 63;
    const int wv   = tid >> 6;

    // ================= P0: fill (aggs=-FLT_MAX, ords=-1, hist=0) + build_uv ==
    {
        int nAgg = p.N * 96, nOrd = p.cap1 + p.cap2;
        int total = nAgg + nOrd + 64;
        for (int i = gtid; i < total; i += gsz) {
            if (i < nAgg) p.AGG1[i] = -FLT_MAX;
            else if (i < nAgg + nOrd) p.ord1[i - nAgg] = -1;
            else p.hist[i - nAgg - nOrd] = 0;
        }
        // build_uv: virtual blocks 0..259 (seg 0..25  x  bx 0..9)
        for (int v = blockIdx.x; v < 260; v += gridDim.x) {
            int seg = v / 10;
            int bx  = v % 10;
            int conv = (bx < 2) ? 0 : 1;
            const float* wa = conv ? p.w2a : p.w1a;
            const float* ba = conv ? p.b2a : p.b1a;
            if (tid < NCONST) {
                float w = wa[tid], b = ba[tid];
                swa[tid] = w; sba[tid] = b;
                stt[tid] = (w != 0.f) ? (-b / w) : INFINITY;
            }
            __syncthreads();
            if (tid < NCONST) {
                int rk = 0;
                for (int l = 0; l < NCONST; ++l) rk += (stt[l] < stt[tid]) ? 1 : 0;
                srk[tid] = rk;
            }
            __syncthreads();
            if (tid == 0) {
                unsigned m = 0;
                for (int k = 0; k < NCONST; ++k) {
                    float w = swa[k];
                    bool act = (w > 0.f) ? (seg > srk[k])
                             : (w < 0.f) ? (seg <= srk[k])
                                         : (sba[k] > 0.f);
                    if (act) m |= (1u << k);
                }
                msk_sh = m;
            }
            __syncthreads();
            unsigned msk = msk_sh;
            if (conv == 0) {
                int idx = bx * 256 + tid;           // < 512
                float u = 0.f, vv = 0.f;
                for (int k = 0; k < NCONST; ++k)
                    if (msk & (1u << k)) { float w = p.w1b[k * 512 + idx]; u = fmaf(swa[k], w, u); vv = fmaf(sba[k], w, vv); }
                vv += p.b1b[idx];
                p.U1[seg * 512 + idx] = u; p.V1[seg * 512 + idx] = vv;
            } else {
                int idx = (bx - 2) * 256 + tid;     // < 2048
                float u = 0.f, vv = 0.f;
                for (int k = 0; k < NCONST; ++k)
                    if (msk & (1u << k)) { float w = p.w2b[k * 2048 + idx]; u = fmaf(swa[k], w, u); vv = fmaf(sba[k], w, vv); }
                vv += p.b2b[idx];
                p.U2[seg * 2048 + idx] = u; p.V2[seg * 2048 + idx] = vv;
            }
            __syncthreads();   // protect swa/sba/msk before next virtual block
        }
    }
    gsync(grid);

    // ================= P1: assign_hist ======================================
    {
        if (tid < NCONST) {
            float w = p.w1a[tid]; t1[tid] = (w != 0.f) ? (-p.b1a[tid] / w) : INFINITY;
            float v2 = p.w2a[tid]; t2[tid] = (v2 != 0.f) ? (-p.b2a[tid] / v2) : INFINITY;
        }
        __syncthreads();
        for (int base = blockIdx.x * NTHR; base < p.E; base += gsz) {
            if (tid < 64) lh[tid] = 0;
            __syncthreads();
            int e = base + tid;
            if (e < p.E) {
                float a = p.ea[e];
                int j1 = 0, j2 = 0;
                for (int k = 0; k < NCONST; ++k) { j1 += (t1[k] < a); j2 += (t2[k] < a); }
                p.segp[e] = j1 | (j2 << 8);
                atomicAdd(&lh[j1], 1); atomicAdd(&lh[32 + j2], 1);
            }
            __syncthreads();
            if (tid < 64 && lh[tid]) atomicAdd(&p.hist[tid], lh[tid]);
            __syncthreads();
        }
    }
    gsync(grid);

    // ================= P2: chunk-aligned exclusive scan (block 0) ===========
    if (blockIdx.x == 0) {
        if (tid == 0) {
            int off = 0;
            for (int j = 0; j < 26; ++j) { p.cur[j] = off; off += ((p.hist[j] + CH1 - 1) / CH1) * CH1; }
        } else if (tid == 1) {
            int off = 0;
            for (int j = 0; j < 26; ++j) { p.cur[32 + j] = off; off += ((p.hist[32 + j] + CH2 - 1) / CH2) * CH2; }
        }
    }
    gsync(grid);

    // ================= P3: scatter ==========================================
    {
        for (int base = blockIdx.x * NTHR; base < p.E; base += gsz) {
            if (tid < 64) lh[tid] = 0;
            __syncthreads();
            int e = base + tid;
            bool valid = e < p.E;
            int j1 = 0, j2 = 0, r1 = 0, r2 = 0;
            if (valid) {
                int pk = p.segp[e]; j1 = pk & 0xFF; j2 = pk >> 8;
                r1 = atomicAdd(&lh[j1], 1); r2 = atomicAdd(&lh[32 + j2], 1);
            }
            __syncthreads();
            if (tid < 64 && lh[tid]) lb[tid] = atomicAdd(&p.cur[tid], lh[tid]);
            __syncthreads();
            if (valid) {
                p.ord1[lb[j1] + r1] = (j1 << 17) | e;
                p.ord2[lb[32 + j2] + r2] = (j2 << 17) | e;
            }
            __syncthreads();
        }
    }
    gsync(grid);

    // ================= P4: edge1 (IC=16, OC=32, half-wave per edge) =========
    {
        int gw = gtid >> 6, nw = gsz >> 6;
        for (int w = gw; w * CH1 < p.cap1; w += nw) {
            int base = w * CH1;
            int pk = p.ord1[base + (lane & (CH1 - 1))];
            int p0 = __builtin_amdgcn_readfirstlane(pk);
            if (p0 < 0) continue;                    // whole-pad chunk
            int seg = p0 >> 17;
            int ev = (pk < 0) ? 0 : (pk & PACK_MASK);
            int sv = p.src[ev], tv = p.tgt[ev];
            float av = p.ea[ev];
            int half = lane >> 5, c = lane & 31;
            float Ur[16], Vr[16];
            {
                const float* Us = p.U1 + seg * 512 + c;
                const float* Vs = p.V1 + seg * 512 + c;
#pragma unroll
                for (int i = 0; i < 16; ++i) { Ur[i] = Us[i * 32]; Vr[i] = Vs[i * 32]; }
            }
#pragma unroll
            for (int t = 0; t < CH1; t += 2) {
                int pA = __builtin_amdgcn_readlane(pk, t);
                int pB = __builtin_amdgcn_readlane(pk, t + 1);
                int sA = __builtin_amdgcn_readlane(sv, t);
                int sB = __builtin_amdgcn_readlane(sv, t + 1);
                int tA = __builtin_amdgcn_readlane(tv, t);
                int tB = __builtin_amdgcn_readlane(tv, t + 1);
                float aA = readlane_f(av, t);
                float aB = readlane_f(av, t + 1);
                const float* xA = p.x + sA * 16;
                const float* xB = p.x + sB * 16;
                float ah = half ? aB : aA;
                int   th = half ? tB : tA;
                int   ph = half ? pB : pA;
                float acc = 0.f;
#pragma unroll
                for (int i = 0; i < 16; ++i) {
                    float xi = half ? xB[i] : xA[i];
                    acc = fmaf(xi, fmaf(ah, Ur[i], Vr[i]), acc);
                }
                if (ph >= 0) atomicMaxFloat(&p.AGG1[th * 32 + c], acc);
            }
        }
    }
    gsync(grid);

    // ================= P5: node1 ============================================
    {
        for (int idx = gtid; idx < p.N * 32; idx += gsz) {
            int n = idx >> 5, c = idx & 31;
            float v = p.AGG1[idx];
            if (v == -FLT_MAX) v = 0.f;
            float acc = v + p.bias1[c];
#pragma unroll
            for (int i = 0; i < 16; ++i) acc = fmaf(p.x[n * 16 + i], p.wr1[i * 32 + c], acc);
            p.H1b[idx] = acc > 0.f ? acc : expm1f(acc);
        }
    }
    gsync(grid);

    // ================= P6: edge2 (IC=32, OC=64, lane = out channel) =========
    {
        int gw = gtid >> 6, nw = gsz >> 6;
        for (int w = gw; w * CH2 < p.cap2; w += nw) {
            int base = w * CH2;
            int pk = p.ord2[base + (lane & (CH2 - 1))];
            int p0 = __builtin_amdgcn_readfirstlane(pk);
            if (p0 < 0) continue;
            int seg = p0 >> 17;
            int ev = (pk < 0) ? 0 : (pk & PACK_MASK);
            int sv = p.src[ev], tv = p.tgt[ev];
            float av = p.ea[ev];
            float Ur[32], Vr[32];
            {
                const float* Us = p.U2 + seg * 2048 + lane;
                const float* Vs = p.V2 + seg * 2048 + lane;
#pragma unroll
                for (int i = 0; i < 32; ++i) { Ur[i] = Us[i * 64]; Vr[i] = Vs[i * 64]; }
            }
#pragma unroll
            for (int t = 0; t < CH2; t += 2) {
                int pA = __builtin_amdgcn_readlane(pk, t);
                int pB = __builtin_amdgcn_readlane(pk, t + 1);
                int sA = __builtin_amdgcn_readlane(sv, t);
                int sB = __builtin_amdgcn_readlane(sv, t + 1);
                int tA = __builtin_amdgcn_readlane(tv, t);
                int tB = __builtin_amdgcn_readlane(tv, t + 1);
                float aA = readlane_f(av, t);
                float aB = readlane_f(av, t + 1);
                const float* xA = p.H1b + sA * 32;
                const float* xB = p.H1b + sB * 32;
                float accA = 0.f, accB = 0.f;
#pragma unroll
                for (int i = 0; i < 32; ++i) {
                    accA = fmaf(xA[i], fmaf(aA, Ur[i], Vr[i]), accA);
                    accB = fmaf(xB[i], fmaf(aB, Ur[i], Vr[i]), accB);
                }
                if (pA >= 0) atomicMaxFloat(&p.AGG2[tA * 64 + lane], accA);
                if (pB >= 0) atomicMaxFloat(&p.AGG2[tB * 64 + lane], accB);
            }
        }
    }
    gsync(grid);

    // ================= P7: tail (node2 + fc1 + fc2 + log_softmax) ===========
    {
        for (int t = tid; t < 1280; t += NTHR) {
            int k = t / 10, j = t - k * 10;
            wTsh[j][k] = p.fc2w[t];
        }
        __syncthreads();
        for (int g = blockIdx.x; g < p.N / 16; g += gridDim.x) {
            int nb = g * 16 + wv * 4;
            {
                const float2* hp = (const float2*)(p.H1b + (size_t)nb * 32);
                ((float2*)&h1sh[wv][0][0])[lane] = hp[lane];
            }
            float b2v = p.bias2[lane];
            float ac0 = p.AGG2[(size_t)(nb + 0) * 64 + lane];
            float ac1 = p.AGG2[(size_t)(nb + 1) * 64 + lane];
            float ac2 = p.AGG2[(size_t)(nb + 2) * 64 + lane];
            float ac3 = p.AGG2[(size_t)(nb + 3) * 64 + lane];
            ac0 = (ac0 == -FLT_MAX ? 0.f : ac0) + b2v;
            ac1 = (ac1 == -FLT_MAX ? 0.f : ac1) + b2v;
            ac2 = (ac2 == -FLT_MAX ? 0.f : ac2) + b2v;
            ac3 = (ac3 == -FLT_MAX ? 0.f : ac3) + b2v;
#pragma unroll 8
            for (int i = 0; i < 32; ++i) {
                float w = p.wr2[i * 64 + lane];
                ac0 = fmaf(h1sh[wv][0][i], w, ac0);
                ac1 = fmaf(h1sh[wv][1][i], w, ac1);
                ac2 = fmaf(h1sh[wv][2][i], w, ac2);
                ac3 = fmaf(h1sh[wv][3][i], w, ac3);
            }
            h2sh[wv][0][lane] = elu_f(ac0);
            h2sh[wv][1][lane] = elu_f(ac1);
            h2sh[wv][2][lane] = elu_f(ac2);
            h2sh[wv][3][lane] = elu_f(ac3);
            float fb1 = p.fc1b[lane], fb2 = p.fc1b[64 + lane];
            float p0 = fb1, p1 = fb1, p2 = fb1, p3 = fb1;
            float q0 = fb2, q1 = fb2, q2 = fb2, q3 = fb2;
#pragma unroll 2
            for (int k4 = 0; k4 < 16; ++k4) {
                int k = k4 * 4;
                float wA0 = p.fc1w[(k + 0) * 128 + lane];
                float wB0 = p.fc1w[(k + 0) * 128 + 64 + lane];
                float wA1 = p.fc1w[(k + 1) * 128 + lane];
                float wB1 = p.fc1w[(k + 1) * 128 + 64 + lane];
                float wA2 = p.fc1w[(k + 2) * 128 + lane];
                float wB2 = p.fc1w[(k + 2) * 128 + 64 + lane];
                float wA3 = p.fc1w[(k + 3) * 128 + lane];
                float wB3 = p.fc1w[(k + 3) * 128 + 64 + lane];
                float4 g0 = ((const float4*)h2sh[wv][0])[k4];
                float4 g1 = ((const float4*)h2sh[wv][1])[k4];
                float4 g2 = ((const float4*)h2sh[wv][2])[k4];
                float4 g3 = ((const float4*)h2sh[wv][3])[k4];
                p0 = fmaf(g0.x, wA0, p0); p0 = fmaf(g0.y, wA1, p0);
                p0 = fmaf(g0.z, wA2, p0); p0 = fmaf(g0.w, wA3, p0);
                q0 = fmaf(g0.x, wB0, q0); q0 = fmaf(g0.y, wB1, q0);
                q0 = fmaf(g0.z, wB2, q0); q0 = fmaf(g0.w, wB3, q0);
                p1 = fmaf(g1.x, wA0, p1); p1 = fmaf(g1.y, wA1, p1);
                p1 = fmaf(g1.z, wA2, p1); p1 = fmaf(g1.w, wA3, p1);
                q1 = fmaf(g1.x, wB0, q1); q1 = fmaf(g1.y, wB1, q1);
                q1 = fmaf(g1.z, wB2, q1); q1 = fmaf(g1.w, wB3, q1);
                p2 = fmaf(g2.x, wA0, p2); p2 = fmaf(g2.y, wA1, p2);
                p2 = fmaf(g2.z, wA2, p2); p2 = fmaf(g2.w, wA3, p2);
                q2 = fmaf(g2.x, wB0, q2); q2 = fmaf(g2.y, wB1, q2);
                q2 = fmaf(g2.z, wB2, q2); q2 = fmaf(g2.w, wB3, q2);
                p3 = fmaf(g3.x, wA0, p3); p3 = fmaf(g3.y, wA1, p3);
                p3 = fmaf(g3.z, wA2, p3); p3 = fmaf(g3.w, wA3, p3);
                q3 = fmaf(g3.x, wB0, q3); q3 = fmaf(g3.y, wB1, q3);
                q3 = fmaf(g3.z, wB2, q3); q3 = fmaf(g3.w, wB3, q3);
            }
            h3sh[wv][0][lane] = elu_f(p0); h3sh[wv][0][64 + lane] = elu_f(q0);
            h3sh[wv][1][lane] = elu_f(p1); h3sh[wv][1][64 + lane] = elu_f(q1);
            h3sh[wv][2][lane] = elu_f(p2); h3sh[wv][2][64 + lane] = elu_f(q2);
            h3sh[wv][3][lane] = elu_f(p3); h3sh[wv][3][64 + lane] = elu_f(q3);
            {
                int n = lane >> 4, j = lane & 15;
                bool act = j < 10;
                int jc = act ? j : 0;
                float a = p.fc2b[jc];
                const float4* h3v = (const float4*)h3sh[wv][n];
                const float4* wv4 = (const float4*)wTsh[jc];
#pragma unroll
                for (int q = 0; q < 32; ++q) {
                    float4 h = h3v[q];
                    float4 w = wv4[q];
                    a = fmaf(h.x, w.x, a);
                    a = fmaf(h.y, w.y, a);
                    a = fmaf(h.z, w.z, a);
                    a = fmaf(h.w, w.w, a);
                }
                float lm = act ? a : -FLT_MAX;
                lm = fmaxf(lm, __shfl_xor(lm, 1, 16));
                lm = fmaxf(lm, __shfl_xor(lm, 2, 16));
                lm = fmaxf(lm, __shfl_xor(lm, 4, 16));
                lm = fmaxf(lm, __shfl_xor(lm, 8, 16));
                float ls = act ? expf(a - lm) : 0.f;
                ls += __shfl_xor(ls, 1, 16);
                ls += __shfl_xor(ls, 2, 16);
                ls += __shfl_xor(ls, 4, 16);
                ls += __shfl_xor(ls, 8, 16);
                if (act) p.out[(size_t)(nb + n) * 10 + j] = a - lm - logf(ls);
            }
        }
    }
}

// ======================= R7 fallback kernels (proven) =======================

__global__ void fill_kernel(float* agg, int nAgg, int* ords, int nOrd, int* hist, int nH) {
    int i = blockIdx.x * blockDim.x + threadIdx.x;
    int stride = gridDim.x * blockDim.x;
    int total = nAgg + nOrd + nH;
    for (; i < total; i += stride) {
        if (i < nAgg) agg[i] = -FLT_MAX;
        else if (i < nAgg + nOrd) ords[i - nAgg] = -1;
        else hist[i - nAgg - nOrd] = 0;
    }
}

__global__ void assign_hist_kernel(const float* __restrict__ ea,
                                   const float* __restrict__ w1a, const float* __restrict__ b1a,
                                   const float* __restrict__ w2a, const float* __restrict__ b2a,
                                   int E, int* __restrict__ segpack, int* __restrict__ hist) {
    __shared__ float t1[NCONST], t2[NCONST];
    __shared__ int lh[64];
    int tid = threadIdx.x;
    if (tid < NCONST) {
        float w = w1a[tid]; t1[tid] = (w != 0.f) ? (-b1a[tid] / w) : INFINITY;
        float v = w2a[tid]; t2[tid] = (v != 0.f) ? (-b2a[tid] / v) : INFINITY;
    }
    if (tid < 64) lh[tid] = 0;
    __syncthreads();
    int e = blockIdx.x * blockDim.x + tid;
    bool valid = e < E;
    if (valid) {
        float a = ea[e];
        int j1 = 0, j2 = 0;
        for (int k = 0; k < NCONST; ++k) { j1 += (t1[k] < a); j2 += (t2[k] < a); }
        segpack[e] = j1 | (j2 << 8);
        atomicAdd(&lh[j1], 1); atomicAdd(&lh[32 + j2], 1);
    }
    __syncthreads();
    if (tid < 64 && lh[tid]) atomicAdd(&hist[tid], lh[tid]);
}

__global__ void scanpad_kernel(const int* __restrict__ hist, int* __restrict__ cur) {
    __shared__ int h[64];
    int tid = threadIdx.x;
    h[tid] = hist[tid];
    __syncthreads();
    if (tid == 0) {
        int off = 0;
        for (int j = 0; j < 26; ++j) { cur[j] = off; off += ((h[j] + CH1 - 1) / CH1) * CH1; }
    } else if (tid == 1) {
        int off = 0;
        for (int j = 0; j < 26; ++j) { cur[32 + j] = off; off += ((h[32 + j] + CH2 - 1) / CH2) * CH2; }
    }
}

__global__ void scatter_kernel(const int* __restrict__ segpack, int E, int* __restrict__ cur,
                               int* __restrict__ order1, int* __restrict__ order2) {
    __shared__ int lh[64], lb[64];
    int tid = threadIdx.x;
    if (tid < 64) lh[tid] = 0;
    __syncthreads();
    int e = blockIdx.x * blockDim.x + tid;
    bool valid = e < E;
    int j1 = 0, j2 = 0, r1 = 0, r2 = 0;
    if (valid) {
        int p = segpack[e]; j1 = p & 0xFF; j2 = p >> 8;
        r1 = atomicAdd(&lh[j1], 1); r2 = atomicAdd(&lh[32 + j2], 1);
    }
    __syncthreads();
    if (tid < 64 && lh[tid]) lb[tid] = atomicAdd(&cur[tid], lh[tid]);
    __syncthreads();
    if (valid) {
        order1[lb[j1] + r1] = (j1 << 17) | e;
        order2[lb[32 + j2] + r2] = (j2 << 17) | e;
    }
}

__global__ void build_uv_fused(const float* w1a, const float* b1a, const float* w1b, const float* b1b,
                               const float* w2a, const float* b2a, const float* w2b, const float* b2b,
                               float* U1, float* V1, float* U2, float* V2) {
    __shared__ float swa[NCONST], sba[NCONST], st[NCONST];
    __shared__ int sr[NCONST];
    __shared__ unsigned msk_sh;
    int seg = blockIdx.y;
    int bx = blockIdx.x;
    int conv = (bx < 2) ? 0 : 1;
    const float* wa = conv ? w2a : w1a;
    const float* ba = conv ? b2a : b1a;
    int tid = threadIdx.x;
    if (tid < NCONST) {
        float w = wa[tid], b = ba[tid];
        swa[tid] = w; sba[tid] = b;
        st[tid] = (w != 0.f) ? (-b / w) : INFINITY;
    }
    __syncthreads();
    if (tid < NCONST) {
        int rk = 0;
        for (int l = 0; l < NCONST; ++l) rk += (st[l] < st[tid]) ? 1 : 0;
        sr[tid] = rk;
    }
    __syncthreads();
    if (tid == 0) {
        unsigned m = 0;
        for (int k = 0; k < NCONST; ++k) {
            float w = swa[k];
            bool act = (w > 0.f) ? (seg > sr[k])
                     : (w < 0.f) ? (seg <= sr[k])
                                 : (sba[k] > 0.f);
            if (act) m |= (1u << k);
        }
        msk_sh = m;
    }
    __syncthreads();
    unsigned msk = msk_sh;
    if (conv == 0) {
        int idx = bx * 256 + tid;
        float u = 0.f, v = 0.f;
        for (int k = 0; k < NCONST; ++k)
            if (msk & (1u << k)) { float w = w1b[k * 512 + idx]; u = fmaf(swa[k], w, u); v = fmaf(sba[k], w, v); }
        v += b1b[idx];
        U1[seg * 512 + idx] = u; V1[seg * 512 + idx] = v;
    } else {
        int idx = (bx - 2) * 256 + tid;
        float u = 0.f, v = 0.f;
        for (int k = 0; k < NCONST; ++k)
            if (msk & (1u << k)) { float w = w2b[k * 2048 + idx]; u = fmaf(swa[k], w, u); v = fmaf(sba[k], w, v); }
        v += b2b[idx];
        U2[seg * 2048 + idx] = u; V2[seg * 2048 + idx] = v;
    }
}

__global__ void edge1_kernel(const float* __restrict__ xin, const int* __restrict__ src,
                             const int* __restrict__ tgt, const float* __restrict__ ea,
                             const int* __restrict__ order, int cap,
                             const float* __restrict__ U, const float* __restrict__ V,
                             float* __restrict__ agg) {
    int wid = (blockIdx.x * blockDim.x + threadIdx.x) >> 6;
    int lane = threadIdx.x & 63;
    int base = wid * CH1;
    if (base >= cap) return;
    int pk = order[base + (lane & (CH1 - 1))];
    int p0 = __builtin_amdgcn_readfirstlane(pk);
    if (p0 < 0) return;
    int seg = p0 >> 17;
    int ev = (pk < 0) ? 0 : (pk & PACK_MASK);
    int sv = src[ev], tv = tgt[ev];
    float av = ea[ev];
    int half = lane >> 5, c = lane & 31;
    float Ur[16], Vr[16];
    {
        const float* Us = U + seg * 512 + c;
        const float* Vs = V + seg * 512 + c;
#pragma unroll
        for (int i = 0; i < 16; ++i) { Ur[i] = Us[i * 32]; Vr[i] = Vs[i * 32]; }
    }
#pragma unroll
    for (int t = 0; t < CH1; t += 2) {
        int pA = __builtin_amdgcn_readlane(pk, t);
        int pB = __builtin_amdgcn_readlane(pk, t + 1);
        int sA = __builtin_amdgcn_readlane(sv, t);
        int sB = __builtin_amdgcn_readlane(sv, t + 1);
        int tA = __builtin_amdgcn_readlane(tv, t);
        int tB = __builtin_amdgcn_readlane(tv, t + 1);
        float aA = readlane_f(av, t);
        float aB = readlane_f(av, t + 1);
        const float* xA = xin + sA * 16;
        const float* xB = xin + sB * 16;
        float ah = half ? aB : aA;
        int   th = half ? tB : tA;
        int   ph = half ? pB : pA;
        float acc = 0.f;
#pragma unroll
        for (int i = 0; i < 16; ++i) {
            float xi = half ? xB[i] : xA[i];
            acc = fmaf(xi, fmaf(ah, Ur[i], Vr[i]), acc);
        }
        if (ph >= 0) atomicMaxFloat(&agg[th * 32 + c], acc);
    }
}

__global__ void edge2_kernel(const float* __restrict__ xin, const int* __restrict__ src,
                             const int* __restrict__ tgt, const float* __restrict__ ea,
                             const int* __restrict__ order, int cap,
                             const float* __restrict__ U, const float* __restrict__ V,
                             float* __restrict__ agg) {
    int wid = (blockIdx.x * blockDim.x + threadIdx.x) >> 6;
    int lane = threadIdx.x & 63;
    int base = wid * CH2;
    if (base >= cap) return;
    int pk = order[base + (lane & (CH2 - 1))];
    int p0 = __builtin_amdgcn_readfirstlane(pk);
    if (p0 < 0) return;
    int seg = p0 >> 17;
    int ev = (pk < 0) ? 0 : (pk & PACK_MASK);
    int sv = src[ev], tv = tgt[ev];
    float av = ea[ev];
    float Ur[32], Vr[32];
    {
        const float* Us = U + seg * 2048 + lane;
        const float* Vs = V + seg * 2048 + lane;
#pragma unroll
        for (int i = 0; i < 32; ++i) { Ur[i] = Us[i * 64]; Vr[i] = Vs[i * 64]; }
    }
#pragma unroll
    for (int t = 0; t < CH2; t += 2) {
        int pA = __builtin_amdgcn_readlane(pk, t);
        int pB = __builtin_amdgcn_readlane(pk, t + 1);
        int sA = __builtin_amdgcn_readlane(sv, t);
        int sB = __builtin_amdgcn_readlane(sv, t + 1);
        int tA = __builtin_amdgcn_readlane(tv, t);
        int tB = __builtin_amdgcn_readlane(tv, t + 1);
        float aA = readlane_f(av, t);
        float aB = readlane_f(av, t + 1);
        const float* xA = xin + sA * 32;
        const float* xB = xin + sB * 32;
        float accA = 0.f, accB = 0.f;
#pragma unroll
        for (int i = 0; i < 32; ++i) {
            accA = fmaf(xA[i], fmaf(aA, Ur[i], Vr[i]), accA);
            accB = fmaf(xB[i], fmaf(aB, Ur[i], Vr[i]), accB);
        }
        if (pA >= 0) atomicMaxFloat(&agg[tA * 64 + lane], accA);
        if (pB >= 0) atomicMaxFloat(&agg[tB * 64 + lane], accB);
    }
}

__global__ void node1_kernel(const float* __restrict__ xin, const float* __restrict__ agg,
                             const float* __restrict__ wroot, const float* __restrict__ bias,
                             float* __restrict__ out, int N) {
    int idx = blockIdx.x * blockDim.x + threadIdx.x;
    if (idx >= N * 32) return;
    int n = idx >> 5, c = idx & 31;
    float v = agg[idx];
    if (v == -FLT_MAX) v = 0.f;
    float acc = v + bias[c];
#pragma unroll
    for (int i = 0; i < 16; ++i) acc = fmaf(xin[n * 16 + i], wroot[i * 32 + c], acc);
    out[idx] = acc > 0.f ? acc : expm1f(acc);
}

__global__ void tail_kernel(const float* __restrict__ h1, const float* __restrict__ agg2,
                            const float* __restrict__ wr2, const float* __restrict__ bias2,
                            const float* __restrict__ fc1w, const float* __restrict__ fc1b,
                            const float* __restrict__ fc2w, const float* __restrict__ fc2b,
                            float* __restrict__ out) {
    __shared__ __align__(16) float h1sh[4][4][32];
    __shared__ __align__(16) float h2sh[4][4][64];
    __shared__ __align__(16) float h3sh[4][4][132];
    __shared__ __align__(16) float wTsh[10][132];
    int tid = threadIdx.x;
    int wv = tid >> 6, lane = tid & 63;
    for (int t = tid; t < 1280; t += 256) {
        int k = t / 10, j = t - k * 10;
        wTsh[j][k] = fc2w[t];
    }
    __syncthreads();
    int nb = blockIdx.x * 16 + wv * 4;
    {
        const float2* hp = (const float2*)(h1 + (size_t)nb * 32);
        ((float2*)&h1sh[wv][0][0])[lane] = hp[lane];
    }
    float b2v = bias2[lane];
    float ac0 = agg2[(size_t)(nb + 0) * 64 + lane];
    float ac1 = agg2[(size_t)(nb + 1) * 64 + lane];
    float ac2 = agg2[(size_t)(nb + 2) * 64 + lane];
    float ac3 = agg2[(size_t)(nb + 3) * 64 + lane];
    ac0 = (ac0 == -FLT_MAX ? 0.f : ac0) + b2v;
    ac1 = (ac1 == -FLT_MAX ? 0.f : ac1) + b2v;
    ac2 = (ac2 == -FLT_MAX ? 0.f : ac2) + b2v;
    ac3 = (ac3 == -FLT_MAX ? 0.f : ac3) + b2v;
#pragma unroll 8
    for (int i = 0; i < 32; ++i) {
        float w = wr2[i * 64 + lane];
        ac0 = fmaf(h1sh[wv][0][i], w, ac0);
        ac1 = fmaf(h1sh[wv][1][i], w, ac1);
        ac2 = fmaf(h1sh[wv][2][i], w, ac2);
        ac3 = fmaf(h1sh[wv][3][i], w, ac3);
    }
    h2sh[wv][0][lane] = elu_f(ac0);
    h2sh[wv][1][lane] = elu_f(ac1);
    h2sh[wv][2][lane] = elu_f(ac2);
    h2sh[wv][3][lane] = elu_f(ac3);
    float fb1 = fc1b[lane], fb2 = fc1b[64 + lane];
    float p0 = fb1, p1 = fb1, p2 = fb1, p3 = fb1;
    float q0 = fb2, q1 = fb2, q2 = fb2, q3 = fb2;
#pragma unroll 2
    for (int k4 = 0; k4 < 16; ++k4) {
        int k = k4 * 4;
        float wA0 = fc1w[(k + 0) * 128 + lane];
        float wB0 = fc1w[(k + 0) * 128 + 64 + lane];
        float wA1 = fc1w[(k + 1) * 128 + lane];
        float wB1 = fc1w[(k + 1) * 128 + 64 + lane];
        float wA2 = fc1w[(k + 2) * 128 + lane];
        float wB2 = fc1w[(k + 2) * 128 + 64 + lane];
        float wA3 = fc1w[(k + 3) * 128 + lane];
        float wB3 = fc1w[(k + 3) * 128 + 64 + lane];
        float4 g0 = ((const float4*)h2sh[wv][0])[k4];
        float4 g1 = ((const float4*)h2sh[wv][1])[k4];
        float4 g2 = ((const float4*)h2sh[wv][2])[k4];
        float4 g3 = ((const float4*)h2sh[wv][3])[k4];
        p0 = fmaf(g0.x, wA0, p0); p0 = fmaf(g0.y, wA1, p0);
        p0 = fmaf(g0.z, wA2, p0); p0 = fmaf(g0.w, wA3, p0);
        q0 = fmaf(g0.x, wB0, q0); q0 = fmaf(g0.y, wB1, q0);
        q0 = fmaf(g0.z, wB2, q0); q0 = fmaf(g0.w, wB3, q0);
        p1 = fmaf(g1.x, wA0, p1); p1 = fmaf(g1.y, wA1, p1);
        p1 = fmaf(g1.z, wA2, p1); p1 = fmaf(g1.w, wA3, p1);
        q1 = fmaf(g1.x, wB0, q1); q1 = fmaf(g1.y, wB1, q1);
        q1 = fmaf(g1.z, wB2, q1); q1 = fmaf(g1.w, wB3, q1);
        p2 = fmaf(g2.x, wA0, p2); p2 = fmaf(g2.y, wA1, p2);
        p2 = fmaf(g2.z, wA2, p2); p2 = fmaf(g2.w, wA3, p2);
        q2 = fmaf(g2.x, wB0, q2); q2 = fmaf(g2.y, wB1, q2);
        q2 = fmaf(g2.z, wB2, q2); q2 = fmaf(g2.w, wB3, q2);
        p3 = fmaf(g3.x, wA0, p3); p3 = fmaf(g3.y, wA1, p3);
        p3 = fmaf(g3.z, wA2, p3); p3 = fmaf(g3.w, wA3, p3);
        q3 = fmaf(g3.x, wB0, q3); q3 = fmaf(g3.y, wB1, q3);
        q3 = fmaf(g3.z, wB2, q3); q3 = fmaf(g3.w, wB3, q3);
    }
    h3sh[wv][0][lane] = elu_f(p0); h3sh[wv][0][64 + lane] = elu_f(q0);
    h3sh[wv][1][lane] = elu_f(p1); h3sh[wv][1][64 + lane] = elu_f(q1);
    h3sh[wv][2][lane] = elu_f(p2); h3sh[wv][2][64 + lane] = elu_f(q2);
    h3sh[wv][3][lane] = elu_f(p3); h3sh[wv][3][64 + lane] = elu_f(q3);
    {
        int n = lane >> 4, j = lane & 15;
        bool act = j < 10;
        int jc = act ? j : 0;
        float a = fc2b[jc];
        const float4* h3v = (const float4*)h3sh[wv][n];
        const float4* wv4 = (const float4*)wTsh[jc];
#pragma unroll
        for (int q = 0; q < 32; ++q) {
            float4 h = h3v[q];
            float4 w = wv4[q];
            a = fmaf(h.x, w.x, a);
            a = fmaf(h.y, w.y, a);
            a = fmaf(h.z, w.z, a);
            a = fmaf(h.w, w.w, a);
        }
        float lm = act ? a : -FLT_MAX;
        lm = fmaxf(lm, __shfl_xor(lm, 1, 16));
        lm = fmaxf(lm, __shfl_xor(lm, 2, 16));
        lm = fmaxf(lm, __shfl_xor(lm, 4, 16));
        lm = fmaxf(lm, __shfl_xor(lm, 8, 16));
        float ls = act ? expf(a - lm) : 0.f;
        ls += __shfl_xor(ls, 1, 16);
        ls += __shfl_xor(ls, 2, 16);
        ls += __shfl_xor(ls, 4, 16);
        ls += __shfl_xor(ls, 8, 16);
        if (act) out[(size_t)(nb + n) * 10 + j] = a - lm - logf(ls);
    }
}

extern "C" void kernel_launch(void* const* d_in, const int* in_sizes, int n_in,
                              void* d_out, int out_size, void* d_ws, size_t ws_size,
                              hipStream_t stream) {
    MegaParams p;
    p.x     = (const float*)d_in[0];
    const int* eidx = (const int*)d_in[1];
    p.ea    = (const float*)d_in[2];
    p.w1a   = (const float*)d_in[3];
    p.b1a   = (const float*)d_in[4];
    p.w1b   = (const float*)d_in[5];
    p.b1b   = (const float*)d_in[6];
    p.wr1   = (const float*)d_in[7];
    p.bias1 = (const float*)d_in[8];
    p.w2a   = (const float*)d_in[9];
    p.b2a   = (const float*)d_in[10];
    p.w2b   = (const float*)d_in[11];
    p.b2b   = (const float*)d_in[12];
    p.wr2   = (const float*)d_in[13];
    p.bias2 = (const float*)d_in[14];
    p.fc1w  = (const float*)d_in[15];
    p.fc1b  = (const float*)d_in[16];
    p.fc2w  = (const float*)d_in[17];
    p.fc2b  = (const float*)d_in[18];
    p.out   = (float*)d_out;

    p.N = in_sizes[0] / 16;   // 20000
    p.E = in_sizes[2];        // 100000
    p.src = eidx;
    p.tgt = eidx + p.E;

    p.cap1 = ((p.E + 26 * (CH1 - 1)) + CH1 - 1) / CH1 * CH1;
    p.cap2 = ((p.E + 26 * (CH2 - 1)) + CH2 - 1) / CH2 * CH2;

    float* ws = (float*)d_ws;
    size_t off = 0;
    p.hist = (int*)(ws + off);      off += 64;
    p.cur  = (int*)(ws + off);      off += 64;
    p.segp = (int*)(ws + off);      off += p.E;
    p.ord1 = (int*)(ws + off);      off += p.cap1;
    p.ord2 = (int*)(ws + off);      off += p.cap2;
    p.U1   = ws + off;              off += 26 * 512;
    p.V1   = ws + off;              off += 26 * 512;
    p.U2   = ws + off;              off += 26 * 2048;
    p.V2   = ws + off;              off += 26 * 2048;
    p.AGG1 = ws + off;              off += (size_t)p.N * 32;
    p.AGG2 = ws + off;              off += (size_t)p.N * 64;
    p.H1b  = ws + off;              off += (size_t)p.N * 32;

    // One-time: max co-resident blocks for the cooperative launch.
    static int megaGrid = -1;
    if (megaGrid < 0) {
        int nb = 0;
        if (hipOccupancyMaxActiveBlocksPerMultiprocessor(&nb, mega_kernel, NTHR, 0) != hipSuccess || nb < 1)
            nb = 1;
        int cus = 256;
        hipDeviceProp_t prop;
        if (hipGetDeviceProperties(&prop, 0) == hipSuccess && prop.multiProcessorCount > 0)
            cus = prop.multiProcessorCount;
        long g = (long)nb * cus;
        megaGrid = (g > NBLK_MAX) ? NBLK_MAX : (int)g;
    }

    void* args[] = { &p };
    hipError_t err = hipLaunchCooperativeKernel((const void*)mega_kernel, dim3(megaGrid),
                                                dim3(NTHR), args, 0, stream);
    if (err == hipSuccess) return;

    // -------- fallback: proven R7 multi-kernel path --------
    fill_kernel<<<512, 256, 0, stream>>>(p.AGG1, p.N * 96, p.ord1, p.cap1 + p.cap2, p.hist, 64);
    assign_hist_kernel<<<(p.E + 255) / 256, 256, 0, stream>>>(p.ea, p.w1a, p.b1a, p.w2a, p.b2a,
                                                              p.E, p.segp, p.hist);
    scanpad_kernel<<<1, 64, 0, stream>>>(p.hist, p.cur);
    scatter_kernel<<<(p.E + 255) / 256, 256, 0, stream>>>(p.segp, p.E, p.cur, p.ord1, p.ord2);
    build_uv_fused<<<dim3(10, 26), 256, 0, stream>>>(p.w1a, p.b1a, p.w1b, p.b1b,
                                                     p.w2a, p.b2a, p.w2b, p.b2b,
                                                     p.U1, p.V1, p.U2, p.V2);
    {
        int waves = p.cap1 / CH1;
        edge1_kernel<<<(waves + 3) / 4, 256, 0, stream>>>(p.x, p.src, p.tgt, p.ea, p.ord1, p.cap1,
                                                          p.U1, p.V1, p.AGG1);
    }
    node1_kernel<<<(p.N * 32 + 255) / 256, 256, 0, stream>>>(p.x, p.AGG1, p.wr1, p.bias1, p.H1b, p.N);
    {
        int waves = p.cap2 / CH2;
        edge2_kernel<<<(waves + 3) / 4, 256, 0, stream>>>(p.H1b, p.src, p.tgt, p.ea, p.ord2, p.cap2,
                                                          p.U2, p.V2, p.AGG2);
    }
    tail_kernel<<<p.N / 16, 256, 0, stream>>>(p.H1b, p.AGG2, p.wr2, p.bias2,
                                              p.fc1w, p.fc1b, p.fc2w, p.fc2b, p.out);
}

// Round 7
// 239.348 us; speedup vs baseline: 2.9388x; 2.9388x over previous
//
#include <hip/hip_runtime.h>
#include <float.h>
#include <math.h>

// NNConv net: 2x edge-conditioned conv (scalar edge attr) + 2 FC + log_softmax.
// W_e = a_e*U_s + V_s over <=26 breakpoint segments of the scalar edge attr.
// Edges bucketed by segment (chunk-aligned so a wave chunk is single-segment).
// R7: tail 4-nodes/wave via loop-order reuse -> 198 us, 9 launches.
// R8/R9: grid-wide cooperative fusion FALSIFIED: 997 us, VALUBusy 2.9% --
// grid.sync + device fences on 8 XCDs serialize through TCC; abandoned.
// R10: back to multi-kernel skeleton +
//  (a) float4 x-row loads in edge1/edge2/node1 (VMEM instr count / 4;
//      the edge kernels are issue-bound: total edge FLOPs ~1 GF ~ 6.5 us),
//  (b) 9 -> 6 kernels + 512B memset: prep = {fill, build_uv, assign_hist}
//      (independent; hist/cur zeroed by hipMemsetAsync), scan folded into
//      scatter (per-block 26-step scan from hist + delta-counter rank).

#define NCONST 25
#define CH1 32   // edges per wave chunk, conv1
#define CH2 16   // edges per wave chunk, conv2
#define PACK_MASK 0x1FFFF  // edge id < 2^17 (E = 100000)
#define TNB 4    // nodes per wave in tail
#define K1_FILL 512
#define K1_UV   260

__device__ __forceinline__ void atomicMaxFloat(float* addr, float val) {
    if (val >= 0.f) atomicMax((int*)addr, __float_as_int(val));
    else            atomicMin((unsigned int*)addr, __float_as_uint(val));
}
__device__ __forceinline__ float readlane_f(float v, int l) {
    return __int_as_float(__builtin_amdgcn_readlane(__float_as_int(v), l));
}
__device__ __forceinline__ float elu_f(float a) {
    return a > 0.f ? a : expm1f(a);
}

struct Params {
    const float *x; const int *src; const int *tgt; const float *ea;
    const float *w1a, *b1a, *w1b, *b1b, *wr1, *bias1;
    const float *w2a, *b2a, *w2b, *b2b, *wr2, *bias2;
    const float *fc1w, *fc1b, *fc2w, *fc2b;
    float *out;
    int *hist, *cur, *segp, *ord1, *ord2;   // hist+cur contiguous (512B memset)
    float *U1, *V1, *U2, *V2, *AGG1, *AGG2, *H1b;  // AGG1/AGG2 contiguous
    int N, E, cap1, cap2;
};

// ===== K1: fused {fill aggs/ords, build_uv, assign_hist}. Per-block role by
// blockIdx range; sections are mutually independent (hist pre-zeroed by memset).
__global__ void prep_kernel(Params p) {
    __shared__ float t1[NCONST], t2[NCONST];
    __shared__ int lh[64];
    __shared__ float swa[NCONST], sba[NCONST], stt[NCONST];
    __shared__ int srk[NCONST];
    __shared__ unsigned msk_sh;
    const int bid = blockIdx.x, tid = threadIdx.x;

    if (bid < K1_FILL) {
        // ---- fill: AGG1/AGG2 = -FLT_MAX, ord1/ord2 = -1 ----
        int nAgg = p.N * 96, total = nAgg + p.cap1 + p.cap2;
        for (int i = bid * 256 + tid; i < total; i += K1_FILL * 256) {
            if (i < nAgg) p.AGG1[i] = -FLT_MAX;
            else p.ord1[i - nAgg] = -1;
        }
    } else if (bid < K1_FILL + K1_UV) {
        // ---- build_uv: virtual block v = seg*10 + bx ----
        int v = bid - K1_FILL;
        int seg = v / 10;
        int bx  = v % 10;
        int conv = (bx < 2) ? 0 : 1;
        const float* wa = conv ? p.w2a : p.w1a;
        const float* ba = conv ? p.b2a : p.b1a;
        if (tid < NCONST) {
            float w = wa[tid], b = ba[tid];
            swa[tid] = w; sba[tid] = b;
            stt[tid] = (w != 0.f) ? (-b / w) : INFINITY;
        }
        __syncthreads();
        if (tid < NCONST) {
            int rk = 0;
            for (int l = 0; l < NCONST; ++l) rk += (stt[l] < stt[tid]) ? 1 : 0;
            srk[tid] = rk;
        }
        __syncthreads();
        if (tid == 0) {
            unsigned m = 0;
            for (int k = 0; k < NCONST; ++k) {
                float w = swa[k];
                bool act = (w > 0.f) ? (seg > srk[k])
                         : (w < 0.f) ? (seg <= srk[k])
                                     : (sba[k] > 0.f);
                if (act) m |= (1u << k);
            }
            msk_sh = m;
        }
        __syncthreads();
        unsigned msk = msk_sh;
        if (conv == 0) {
            int idx = bx * 256 + tid;           // < 512
            float u = 0.f, vv = 0.f;
            for (int k = 0; k < NCONST; ++k)
                if (msk & (1u << k)) { float w = p.w1b[k * 512 + idx]; u = fmaf(swa[k], w, u); vv = fmaf(sba[k], w, vv); }
            vv += p.b1b[idx];
            p.U1[seg * 512 + idx] = u; p.V1[seg * 512 + idx] = vv;
        } else {
            int idx = (bx - 2) * 256 + tid;     // < 2048
            float u = 0.f, vv = 0.f;
            for (int k = 0; k < NCONST; ++k)
                if (msk & (1u << k)) { float w = p.w2b[k * 2048 + idx]; u = fmaf(swa[k], w, u); vv = fmaf(sba[k], w, vv); }
            vv += p.b2b[idx];
            p.U2[seg * 2048 + idx] = u; p.V2[seg * 2048 + idx] = vv;
        }
    } else {
        // ---- assign_hist: one 256-edge tile per block ----
        if (tid < NCONST) {
            float w = p.w1a[tid]; t1[tid] = (w != 0.f) ? (-p.b1a[tid] / w) : INFINITY;
            float v = p.w2a[tid]; t2[tid] = (v != 0.f) ? (-p.b2a[tid] / v) : INFINITY;
        }
        if (tid < 64) lh[tid] = 0;
        __syncthreads();
        int e = (bid - K1_FILL - K1_UV) * 256 + tid;
        if (e < p.E) {
            float a = p.ea[e];
            int j1 = 0, j2 = 0;
            for (int k = 0; k < NCONST; ++k) { j1 += (t1[k] < a); j2 += (t2[k] < a); }
            p.segp[e] = j1 | (j2 << 8);
            atomicAdd(&lh[j1], 1); atomicAdd(&lh[32 + j2], 1);
        }
        __syncthreads();
        if (tid < 64 && lh[tid]) atomicAdd(&p.hist[tid], lh[tid]);
    }
}

// ===== K2: scatter with in-block scan (scanpad folded in). cur starts at 0
// (memset) and acts as a per-bin delta counter; base offsets recomputed
// per-block from hist (26 serial adds in 2 lanes, negligible).
__global__ void scatter_scan_kernel(Params p) {
    __shared__ int h[64], sbase[64], lh[64], lb[64];
    int tid = threadIdx.x;
    if (tid < 64) h[tid] = p.hist[tid];
    __syncthreads();
    if (tid == 0) {
        int off = 0;
        for (int j = 0; j < 26; ++j) { sbase[j] = off; off += ((h[j] + CH1 - 1) / CH1) * CH1; }
    } else if (tid == 1) {
        int off = 0;
        for (int j = 0; j < 26; ++j) { sbase[32 + j] = off; off += ((h[32 + j] + CH2 - 1) / CH2) * CH2; }
    }
    if (tid < 64) lh[tid] = 0;
    __syncthreads();
    int e = blockIdx.x * 256 + tid;
    bool valid = e < p.E;
    int j1 = 0, j2 = 0, r1 = 0, r2 = 0;
    if (valid) {
        int pk = p.segp[e]; j1 = pk & 0xFF; j2 = pk >> 8;
        r1 = atomicAdd(&lh[j1], 1); r2 = atomicAdd(&lh[32 + j2], 1);
    }
    __syncthreads();
    if (tid < 64 && lh[tid]) lb[tid] = sbase[tid] + atomicAdd(&p.cur[tid], lh[tid]);
    __syncthreads();
    if (valid) {
        p.ord1[lb[j1] + r1] = (j1 << 17) | e;
        p.ord2[lb[32 + j2] + r2] = (j2 << 17) | e;
    }
}

// ===== edge1: IC=16, OC=32, half-wave per edge (2 edges/iter), float4 rows.
__global__ void edge1_kernel(Params p) {
    int wid = (blockIdx.x * blockDim.x + threadIdx.x) >> 6;
    int lane = threadIdx.x & 63;
    int base = wid * CH1;
    if (base >= p.cap1) return;
    int pk = p.ord1[base + (lane & (CH1 - 1))];
    int p0 = __builtin_amdgcn_readfirstlane(pk);
    if (p0 < 0) return;                        // whole-pad chunk past used region
    int seg = p0 >> 17;
    int ev = (pk < 0) ? 0 : (pk & PACK_MASK);
    int sv = p.src[ev], tv = p.tgt[ev];
    float av = p.ea[ev];
    int half = lane >> 5, c = lane & 31;
    float Ur[16], Vr[16];
    {
        const float* Us = p.U1 + seg * 512 + c;
        const float* Vs = p.V1 + seg * 512 + c;
#pragma unroll
        for (int i = 0; i < 16; ++i) { Ur[i] = Us[i * 32]; Vr[i] = Vs[i * 32]; }
    }
#pragma unroll
    for (int t = 0; t < CH1; t += 2) {
        int pA = __builtin_amdgcn_readlane(pk, t);
        int pB = __builtin_amdgcn_readlane(pk, t + 1);
        int sA = __builtin_amdgcn_readlane(sv, t);
        int sB = __builtin_amdgcn_readlane(sv, t + 1);
        int tA = __builtin_amdgcn_readlane(tv, t);
        int tB = __builtin_amdgcn_readlane(tv, t + 1);
        float aA = readlane_f(av, t);
        float aB = readlane_f(av, t + 1);
        float ah = half ? aB : aA;
        int   th = half ? tB : tA;
        int   ph = half ? pB : pA;
        // per-lane row pointer: half-wave A reads row sA, half-wave B row sB
        const float4* xr = (const float4*)(p.x + (half ? sB : sA) * 16);
        float acc = 0.f;
#pragma unroll
        for (int q = 0; q < 4; ++q) {
            float4 v = xr[q];
            acc = fmaf(v.x, fmaf(ah, Ur[q * 4 + 0], Vr[q * 4 + 0]), acc);
            acc = fmaf(v.y, fmaf(ah, Ur[q * 4 + 1], Vr[q * 4 + 1]), acc);
            acc = fmaf(v.z, fmaf(ah, Ur[q * 4 + 2], Vr[q * 4 + 2]), acc);
            acc = fmaf(v.w, fmaf(ah, Ur[q * 4 + 3], Vr[q * 4 + 3]), acc);
        }
        if (ph >= 0) atomicMaxFloat(&p.AGG1[th * 32 + c], acc);
    }
}

// ===== edge2: IC=32, OC=64, lane = out channel, A/B edge pair, float4 rows.
__global__ void edge2_kernel(Params p) {
    int wid = (blockIdx.x * blockDim.x + threadIdx.x) >> 6;
    int lane = threadIdx.x & 63;
    int base = wid * CH2;
    if (base >= p.cap2) return;
    int pk = p.ord2[base + (lane & (CH2 - 1))];
    int p0 = __builtin_amdgcn_readfirstlane(pk);
    if (p0 < 0) return;
    int seg = p0 >> 17;
    int ev = (pk < 0) ? 0 : (pk & PACK_MASK);
    int sv = p.src[ev], tv = p.tgt[ev];
    float av = p.ea[ev];
    float Ur[32], Vr[32];
    {
        const float* Us = p.U2 + seg * 2048 + lane;
        const float* Vs = p.V2 + seg * 2048 + lane;
#pragma unroll
        for (int i = 0; i < 32; ++i) { Ur[i] = Us[i * 64]; Vr[i] = Vs[i * 64]; }
    }
#pragma unroll
    for (int t = 0; t < CH2; t += 2) {
        int pA = __builtin_amdgcn_readlane(pk, t);
        int pB = __builtin_amdgcn_readlane(pk, t + 1);
        int sA = __builtin_amdgcn_readlane(sv, t);
        int sB = __builtin_amdgcn_readlane(sv, t + 1);
        int tA = __builtin_amdgcn_readlane(tv, t);
        int tB = __builtin_amdgcn_readlane(tv, t + 1);
        float aA = readlane_f(av, t);
        float aB = readlane_f(av, t + 1);
        const float4* xa4 = (const float4*)(p.H1b + sA * 32);
        const float4* xb4 = (const float4*)(p.H1b + sB * 32);
        float accA = 0.f, accB = 0.f;
#pragma unroll
        for (int q = 0; q < 8; ++q) {
            float4 va = xa4[q];
            float4 vb = xb4[q];
            accA = fmaf(va.x, fmaf(aA, Ur[q * 4 + 0], Vr[q * 4 + 0]), accA);
            accB = fmaf(vb.x, fmaf(aB, Ur[q * 4 + 0], Vr[q * 4 + 0]), accB);
            accA = fmaf(va.y, fmaf(aA, Ur[q * 4 + 1], Vr[q * 4 + 1]), accA);
            accB = fmaf(vb.y, fmaf(aB, Ur[q * 4 + 1], Vr[q * 4 + 1]), accB);
            accA = fmaf(va.z, fmaf(aA, Ur[q * 4 + 2], Vr[q * 4 + 2]), accA);
            accB = fmaf(vb.z, fmaf(aB, Ur[q * 4 + 2], Vr[q * 4 + 2]), accB);
            accA = fmaf(va.w, fmaf(aA, Ur[q * 4 + 3], Vr[q * 4 + 3]), accA);
            accB = fmaf(vb.w, fmaf(aB, Ur[q * 4 + 3], Vr[q * 4 + 3]), accB);
        }
        if (pA >= 0) atomicMaxFloat(&p.AGG2[tA * 64 + lane], accA);
        if (pB >= 0) atomicMaxFloat(&p.AGG2[tB * 64 + lane], accB);
    }
}

// ===== node1: out = elu( fixup(agg) + x @ wr1 + bias1 ), float4 row loads.
__global__ void node1_kernel(Params p) {
    int idx = blockIdx.x * blockDim.x + threadIdx.x;
    if (idx >= p.N * 32) return;
    int n = idx >> 5, c = idx & 31;
    float v = p.AGG1[idx];
    if (v == -FLT_MAX) v = 0.f;
    float acc = v + p.bias1[c];
    const float4* xr = (const float4*)(p.x + n * 16);
#pragma unroll
    for (int q = 0; q < 4; ++q) {
        float4 h = xr[q];
        acc = fmaf(h.x, p.wr1[(q * 4 + 0) * 32 + c], acc);
        acc = fmaf(h.y, p.wr1[(q * 4 + 1) * 32 + c], acc);
        acc = fmaf(h.z, p.wr1[(q * 4 + 2) * 32 + c], acc);
        acc = fmaf(h.w, p.wr1[(q * 4 + 3) * 32 + c], acc);
    }
    p.H1b[idx] = elu_f(acc);
}

// ===== tail: node2 + fc1 + fc2 + log_softmax. 4 nodes/wave, zero local
// arrays (R4-R6 lesson: allocator pins 64-VGPR budget; register arrays spill).
__global__ void tail_kernel(Params p) {
    __shared__ __align__(16) float h1sh[4][TNB][32];
    __shared__ __align__(16) float h2sh[4][TNB][64];
    __shared__ __align__(16) float h3sh[4][TNB][132];   // +4 pad
    __shared__ __align__(16) float wTsh[10][132];       // fc2w transposed
    int tid = threadIdx.x;
    int wv = tid >> 6, lane = tid & 63;

    for (int t = tid; t < 1280; t += 256) {
        int k = t / 10, j = t - k * 10;
        wTsh[j][k] = p.fc2w[t];
    }
    __syncthreads();   // only barrier; everything below is wave-local

    int nb = blockIdx.x * (4 * TNB) + wv * TNB;

    {
        const float2* hp = (const float2*)(p.H1b + (size_t)nb * 32);
        ((float2*)&h1sh[wv][0][0])[lane] = hp[lane];
    }

    // phase 1: node2
    float b2v = p.bias2[lane];
    float ac0 = p.AGG2[(size_t)(nb + 0) * 64 + lane];
    float ac1 = p.AGG2[(size_t)(nb + 1) * 64 + lane];
    float ac2 = p.AGG2[(size_t)(nb + 2) * 64 + lane];
    float ac3 = p.AGG2[(size_t)(nb + 3) * 64 + lane];
    ac0 = (ac0 == -FLT_MAX ? 0.f : ac0) + b2v;
    ac1 = (ac1 == -FLT_MAX ? 0.f : ac1) + b2v;
    ac2 = (ac2 == -FLT_MAX ? 0.f : ac2) + b2v;
    ac3 = (ac3 == -FLT_MAX ? 0.f : ac3) + b2v;
#pragma unroll 8
    for (int i = 0; i < 32; ++i) {
        float w = p.wr2[i * 64 + lane];
        ac0 = fmaf(h1sh[wv][0][i], w, ac0);
        ac1 = fmaf(h1sh[wv][1][i], w, ac1);
        ac2 = fmaf(h1sh[wv][2][i], w, ac2);
        ac3 = fmaf(h1sh[wv][3][i], w, ac3);
    }
    h2sh[wv][0][lane] = elu_f(ac0);
    h2sh[wv][1][lane] = elu_f(ac1);
    h2sh[wv][2][lane] = elu_f(ac2);
    h2sh[wv][3][lane] = elu_f(ac3);

    // phase 2: fc1 (H2=64 -> 16 float4 groups)
    float fb1 = p.fc1b[lane], fb2 = p.fc1b[64 + lane];
    float p0 = fb1, p1 = fb1, p2 = fb1, p3 = fb1;
    float q0 = fb2, q1 = fb2, q2 = fb2, q3 = fb2;
#pragma unroll 2
    for (int k4 = 0; k4 < 16; ++k4) {
        int k = k4 * 4;
        float wA0 = p.fc1w[(k + 0) * 128 + lane];
        float wB0 = p.fc1w[(k + 0) * 128 + 64 + lane];
        float wA1 = p.fc1w[(k + 1) * 128 + lane];
        float wB1 = p.fc1w[(k + 1) * 128 + 64 + lane];
        float wA2 = p.fc1w[(k + 2) * 128 + lane];
        float wB2 = p.fc1w[(k + 2) * 128 + 64 + lane];
        float wA3 = p.fc1w[(k + 3) * 128 + lane];
        float wB3 = p.fc1w[(k + 3) * 128 + 64 + lane];
        float4 g0 = ((const float4*)h2sh[wv][0])[k4];
        float4 g1 = ((const float4*)h2sh[wv][1])[k4];
        float4 g2 = ((const float4*)h2sh[wv][2])[k4];
        float4 g3 = ((const float4*)h2sh[wv][3])[k4];
        p0 = fmaf(g0.x, wA0, p0); p0 = fmaf(g0.y, wA1, p0);
        p0 = fmaf(g0.z, wA2, p0); p0 = fmaf(g0.w, wA3, p0);
        q0 = fmaf(g0.x, wB0, q0); q0 = fmaf(g0.y, wB1, q0);
        q0 = fmaf(g0.z, wB2, q0); q0 = fmaf(g0.w, wB3, q0);
        p1 = fmaf(g1.x, wA0, p1); p1 = fmaf(g1.y, wA1, p1);
        p1 = fmaf(g1.z, wA2, p1); p1 = fmaf(g1.w, wA3, p1);
        q1 = fmaf(g1.x, wB0, q1); q1 = fmaf(g1.y, wB1, q1);
        q1 = fmaf(g1.z, wB2, q1); q1 = fmaf(g1.w, wB3, q1);
        p2 = fmaf(g2.x, wA0, p2); p2 = fmaf(g2.y, wA1, p2);
        p2 = fmaf(g2.z, wA2, p2); p2 = fmaf(g2.w, wA3, p2);
        q2 = fmaf(g2.x, wB0, q2); q2 = fmaf(g2.y, wB1, q2);
        q2 = fmaf(g2.z, wB2, q2); q2 = fmaf(g2.w, wB3, q2);
        p3 = fmaf(g3.x, wA0, p3); p3 = fmaf(g3.y, wA1, p3);
        p3 = fmaf(g3.z, wA2, p3); p3 = fmaf(g3.w, wA3, p3);
        q3 = fmaf(g3.x, wB0, q3); q3 = fmaf(g3.y, wB1, q3);
        q3 = fmaf(g3.z, wB2, q3); q3 = fmaf(g3.w, wB3, q3);
    }
    h3sh[wv][0][lane] = elu_f(p0); h3sh[wv][0][64 + lane] = elu_f(q0);
    h3sh[wv][1][lane] = elu_f(p1); h3sh[wv][1][64 + lane] = elu_f(q1);
    h3sh[wv][2][lane] = elu_f(p2); h3sh[wv][2][64 + lane] = elu_f(q2);
    h3sh[wv][3][lane] = elu_f(p3); h3sh[wv][3][64 + lane] = elu_f(q3);

    // phase 3: fc2 + log_softmax
    {
        int n = lane >> 4, j = lane & 15;
        bool act = j < 10;
        int jc = act ? j : 0;
        float a = p.fc2b[jc];
        const float4* h3v = (const float4*)h3sh[wv][n];
        const float4* wv4 = (const float4*)wTsh[jc];
#pragma unroll
        for (int q = 0; q < 32; ++q) {
            float4 h = h3v[q];
            float4 w = wv4[q];
            a = fmaf(h.x, w.x, a);
            a = fmaf(h.y, w.y, a);
            a = fmaf(h.z, w.z, a);
            a = fmaf(h.w, w.w, a);
        }
        float lm = act ? a : -FLT_MAX;
        lm = fmaxf(lm, __shfl_xor(lm, 1, 16));
        lm = fmaxf(lm, __shfl_xor(lm, 2, 16));
        lm = fmaxf(lm, __shfl_xor(lm, 4, 16));
        lm = fmaxf(lm, __shfl_xor(lm, 8, 16));
        float ls = act ? expf(a - lm) : 0.f;
        ls += __shfl_xor(ls, 1, 16);
        ls += __shfl_xor(ls, 2, 16);
        ls += __shfl_xor(ls, 4, 16);
        ls += __shfl_xor(ls, 8, 16);
        if (act) p.out[(size_t)(nb + n) * 10 + j] = a - lm - logf(ls);
    }
}

extern "C" void kernel_launch(void* const* d_in, const int* in_sizes, int n_in,
                              void* d_out, int out_size, void* d_ws, size_t ws_size,
                              hipStream_t stream) {
    Params p;
    p.x     = (const float*)d_in[0];
    const int* eidx = (const int*)d_in[1];
    p.ea    = (const float*)d_in[2];
    p.w1a   = (const float*)d_in[3];
    p.b1a   = (const float*)d_in[4];
    p.w1b   = (const float*)d_in[5];
    p.b1b   = (const float*)d_in[6];
    p.wr1   = (const float*)d_in[7];
    p.bias1 = (const float*)d_in[8];
    p.w2a   = (const float*)d_in[9];
    p.b2a   = (const float*)d_in[10];
    p.w2b   = (const float*)d_in[11];
    p.b2b   = (const float*)d_in[12];
    p.wr2   = (const float*)d_in[13];
    p.bias2 = (const float*)d_in[14];
    p.fc1w  = (const float*)d_in[15];
    p.fc1b  = (const float*)d_in[16];
    p.fc2w  = (const float*)d_in[17];
    p.fc2b  = (const float*)d_in[18];
    p.out   = (float*)d_out;

    p.N = in_sizes[0] / 16;   // 20000
    p.E = in_sizes[2];        // 100000
    p.src = eidx;
    p.tgt = eidx + p.E;

    p.cap1 = ((p.E + 26 * (CH1 - 1)) + CH1 - 1) / CH1 * CH1;
    p.cap2 = ((p.E + 26 * (CH2 - 1)) + CH2 - 1) / CH2 * CH2;

    float* ws = (float*)d_ws;
    size_t off = 0;
    p.hist = (int*)(ws + off);      off += 64;   // hist+cur contiguous: 512B memset
    p.cur  = (int*)(ws + off);      off += 64;
    p.segp = (int*)(ws + off);      off += p.E;
    p.ord1 = (int*)(ws + off);      off += p.cap1;   // ord1/ord2 contiguous
    p.ord2 = (int*)(ws + off);      off += p.cap2;
    p.U1   = ws + off;              off += 26 * 512;
    p.V1   = ws + off;              off += 26 * 512;
    p.U2   = ws + off;              off += 26 * 2048;
    p.V2   = ws + off;              off += 26 * 2048;
    p.AGG1 = ws + off;              off += (size_t)p.N * 32;   // AGG1/AGG2 contiguous
    p.AGG2 = ws + off;              off += (size_t)p.N * 64;
    p.H1b  = ws + off;              off += (size_t)p.N * 32;

    const int nAssign = (p.E + 255) / 256;   // 391

    // 0. hist + cur = 0 (512 B; graph-capturable)
    hipMemsetAsync(p.hist, 0, 512, stream);
    // 1. fused fill + build_uv + assign_hist
    prep_kernel<<<K1_FILL + K1_UV + nAssign, 256, 0, stream>>>(p);
    // 2. scatter with in-block scan (scanpad folded in)
    scatter_scan_kernel<<<nAssign, 256, 0, stream>>>(p);
    // 3. conv1 edges
    {
        int waves = p.cap1 / CH1;
        edge1_kernel<<<(waves + 3) / 4, 256, 0, stream>>>(p);
    }
    // 4. conv1 node update
    node1_kernel<<<(p.N * 32 + 255) / 256, 256, 0, stream>>>(p);
    // 5. conv2 edges
    {
        int waves = p.cap2 / CH2;
        edge2_kernel<<<(waves + 3) / 4, 256, 0, stream>>>(p);
    }
    // 6. fused node2 + fc1 + fc2 + log_softmax
    tail_kernel<<<p.N / 16, 256, 0, stream>>>(p);
}

// Round 8
// 189.651 us; speedup vs baseline: 3.7089x; 1.2620x over previous
//
#include <hip/hip_runtime.h>
#include <float.h>
#include <math.h>

// NNConv net: 2x edge-conditioned conv (scalar edge attr) + 2 FC + log_softmax.
// W_e = a_e*U_s + V_s over <=26 breakpoint segments of the scalar edge attr.
// Edges bucketed by segment (chunk-aligned so a wave chunk is single-segment).
// R7: tail 4-nodes/wave loop-order reuse -> 198 us, 9 launches, no dispatch
//     over 42 us (fill).
// R8/R9: grid-wide cooperative fusion FALSIFIED (997 us, VALUBusy 2.9%).
// R10: prep fusion (9->6 launches, ~ -10 us) BUT float4 x-row loads in edge2
//     REGRESSED it 42 -> 94 us: per-lane VMEM replaced wave-uniform s_load,
//     pressure > pinned 64-VGPR budget -> Ur/Vr spilled (WRITE 89 MB).
// R11: keep prep fusion + scatter_scan + memset; revert edge1/edge2/node1/tail
//     to exact R7 bodies (wave-uniform scalar x loads, individual args).

#define NCONST 25
#define CH1 32   // edges per wave chunk, conv1
#define CH2 16   // edges per wave chunk, conv2
#define PACK_MASK 0x1FFFF  // edge id < 2^17 (E = 100000)
#define TNB 4    // nodes per wave in tail
#define K1_FILL 64
#define K1_UV   260

__device__ __forceinline__ void atomicMaxFloat(float* addr, float val) {
    if (val >= 0.f) atomicMax((int*)addr, __float_as_int(val));
    else            atomicMin((unsigned int*)addr, __float_as_uint(val));
}
__device__ __forceinline__ float readlane_f(float v, int l) {
    return __int_as_float(__builtin_amdgcn_readlane(__float_as_int(v), l));
}
__device__ __forceinline__ float elu_f(float a) {
    return a > 0.f ? a : expm1f(a);
}

struct PrepParams {
    const float *ea;
    const float *w1a, *b1a, *w1b, *b1b;
    const float *w2a, *b2a, *w2b, *b2b;
    int *hist, *segp, *ord1;               // ord1/ord2 contiguous; fill covers both
    float *U1, *V1, *U2, *V2, *AGG1;       // AGG1/AGG2 contiguous
    int N, E, capSum;
};

// ===== K1: fused {fill aggs/ords, build_uv, assign_hist}. Block role by
// blockIdx range; sections mutually independent (hist pre-zeroed by memset).
__global__ void prep_kernel(PrepParams p) {
    __shared__ float t1[NCONST], t2[NCONST];
    __shared__ int lh[64];
    __shared__ float swa[NCONST], sba[NCONST], stt[NCONST];
    __shared__ int srk[NCONST];
    __shared__ unsigned msk_sh;
    const int bid = blockIdx.x, tid = threadIdx.x;

    if (bid < K1_FILL) {
        // ---- fill: AGG1/AGG2 = -FLT_MAX (float pattern), ord1/ord2 = -1 ----
        int nAgg = p.N * 96, total = nAgg + p.capSum;
        for (int i = bid * 256 + tid; i < total; i += K1_FILL * 256) {
            if (i < nAgg) p.AGG1[i] = -FLT_MAX;
            else p.ord1[i - nAgg] = -1;
        }
    } else if (bid < K1_FILL + K1_UV) {
        // ---- build_uv: virtual block v = seg*10 + bx ----
        int v = bid - K1_FILL;
        int seg = v / 10;
        int bx  = v % 10;
        int conv = (bx < 2) ? 0 : 1;
        const float* wa = conv ? p.w2a : p.w1a;
        const float* ba = conv ? p.b2a : p.b1a;
        if (tid < NCONST) {
            float w = wa[tid], b = ba[tid];
            swa[tid] = w; sba[tid] = b;
            stt[tid] = (w != 0.f) ? (-b / w) : INFINITY;
        }
        __syncthreads();
        if (tid < NCONST) {
            int rk = 0;
            for (int l = 0; l < NCONST; ++l) rk += (stt[l] < stt[tid]) ? 1 : 0;
            srk[tid] = rk;
        }
        __syncthreads();
        if (tid == 0) {
            unsigned m = 0;
            for (int k = 0; k < NCONST; ++k) {
                float w = swa[k];
                bool act = (w > 0.f) ? (seg > srk[k])
                         : (w < 0.f) ? (seg <= srk[k])
                                     : (sba[k] > 0.f);
                if (act) m |= (1u << k);
            }
            msk_sh = m;
        }
        __syncthreads();
        unsigned msk = msk_sh;
        if (conv == 0) {
            int idx = bx * 256 + tid;           // < 512
            float u = 0.f, vv = 0.f;
            for (int k = 0; k < NCONST; ++k)
                if (msk & (1u << k)) { float w = p.w1b[k * 512 + idx]; u = fmaf(swa[k], w, u); vv = fmaf(sba[k], w, vv); }
            vv += p.b1b[idx];
            p.U1[seg * 512 + idx] = u; p.V1[seg * 512 + idx] = vv;
        } else {
            int idx = (bx - 2) * 256 + tid;     // < 2048
            float u = 0.f, vv = 0.f;
            for (int k = 0; k < NCONST; ++k)
                if (msk & (1u << k)) { float w = p.w2b[k * 2048 + idx]; u = fmaf(swa[k], w, u); vv = fmaf(sba[k], w, vv); }
            vv += p.b2b[idx];
            p.U2[seg * 2048 + idx] = u; p.V2[seg * 2048 + idx] = vv;
        }
    } else {
        // ---- assign_hist: one 256-edge tile per block ----
        if (tid < NCONST) {
            float w = p.w1a[tid]; t1[tid] = (w != 0.f) ? (-p.b1a[tid] / w) : INFINITY;
            float v = p.w2a[tid]; t2[tid] = (v != 0.f) ? (-p.b2a[tid] / v) : INFINITY;
        }
        if (tid < 64) lh[tid] = 0;
        __syncthreads();
        int e = (bid - K1_FILL - K1_UV) * 256 + tid;
        if (e < p.E) {
            float a = p.ea[e];
            int j1 = 0, j2 = 0;
            for (int k = 0; k < NCONST; ++k) { j1 += (t1[k] < a); j2 += (t2[k] < a); }
            p.segp[e] = j1 | (j2 << 8);
            atomicAdd(&lh[j1], 1); atomicAdd(&lh[32 + j2], 1);
        }
        __syncthreads();
        if (tid < 64 && lh[tid]) atomicAdd(&p.hist[tid], lh[tid]);
    }
}

// ===== K2: scatter with in-block scan (scanpad folded in). cur starts at 0
// (memset) as per-bin delta counter; base offsets recomputed per-block from
// hist (26 serial adds in 2 lanes, negligible).
__global__ void scatter_scan_kernel(const int* __restrict__ segpack, int E,
                                    const int* __restrict__ hist, int* __restrict__ cur,
                                    int* __restrict__ order1, int* __restrict__ order2) {
    __shared__ int h[64], sbase[64], lh[64], lb[64];
    int tid = threadIdx.x;
    if (tid < 64) h[tid] = hist[tid];
    __syncthreads();
    if (tid == 0) {
        int off = 0;
        for (int j = 0; j < 26; ++j) { sbase[j] = off; off += ((h[j] + CH1 - 1) / CH1) * CH1; }
    } else if (tid == 1) {
        int off = 0;
        for (int j = 0; j < 26; ++j) { sbase[32 + j] = off; off += ((h[32 + j] + CH2 - 1) / CH2) * CH2; }
    }
    if (tid < 64) lh[tid] = 0;
    __syncthreads();
    int e = blockIdx.x * 256 + tid;
    bool valid = e < E;
    int j1 = 0, j2 = 0, r1 = 0, r2 = 0;
    if (valid) {
        int pk = segpack[e]; j1 = pk & 0xFF; j2 = pk >> 8;
        r1 = atomicAdd(&lh[j1], 1); r2 = atomicAdd(&lh[32 + j2], 1);
    }
    __syncthreads();
    if (tid < 64 && lh[tid]) lb[tid] = sbase[tid] + atomicAdd(&cur[tid], lh[tid]);
    __syncthreads();
    if (valid) {
        order1[lb[j1] + r1] = (j1 << 17) | e;
        order2[lb[32 + j2] + r2] = (j2 << 17) | e;
    }
}

// ===== edge1: IC=16, OC=32, half-wave per edge (2 edges/iter). R7 body:
// wave-uniform scalar x loads (s_load path), per-lane U/V register cache.
__global__ void edge1_kernel(const float* __restrict__ xin, const int* __restrict__ src,
                             const int* __restrict__ tgt, const float* __restrict__ ea,
                             const int* __restrict__ order, int cap,
                             const float* __restrict__ U, const float* __restrict__ V,
                             float* __restrict__ agg) {
    int wid = (blockIdx.x * blockDim.x + threadIdx.x) >> 6;
    int lane = threadIdx.x & 63;
    int base = wid * CH1;
    if (base >= cap) return;
    int pk = order[base + (lane & (CH1 - 1))];
    int p0 = __builtin_amdgcn_readfirstlane(pk);
    if (p0 < 0) return;                        // whole-pad chunk past used region
    int seg = p0 >> 17;
    int ev = (pk < 0) ? 0 : (pk & PACK_MASK);
    int sv = src[ev], tv = tgt[ev];
    float av = ea[ev];
    int half = lane >> 5, c = lane & 31;
    float Ur[16], Vr[16];
    {
        const float* Us = U + seg * 512 + c;
        const float* Vs = V + seg * 512 + c;
#pragma unroll
        for (int i = 0; i < 16; ++i) { Ur[i] = Us[i * 32]; Vr[i] = Vs[i * 32]; }
    }
#pragma unroll
    for (int t = 0; t < CH1; t += 2) {
        int pA = __builtin_amdgcn_readlane(pk, t);
        int pB = __builtin_amdgcn_readlane(pk, t + 1);
        int sA = __builtin_amdgcn_readlane(sv, t);
        int sB = __builtin_amdgcn_readlane(sv, t + 1);
        int tA = __builtin_amdgcn_readlane(tv, t);
        int tB = __builtin_amdgcn_readlane(tv, t + 1);
        float aA = readlane_f(av, t);
        float aB = readlane_f(av, t + 1);
        const float* xA = xin + sA * 16;
        const float* xB = xin + sB * 16;
        float ah = half ? aB : aA;
        int   th = half ? tB : tA;
        int   ph = half ? pB : pA;
        float acc = 0.f;
#pragma unroll
        for (int i = 0; i < 16; ++i) {
            float xi = half ? xB[i] : xA[i];
            acc = fmaf(xi, fmaf(ah, Ur[i], Vr[i]), acc);
        }
        if (ph >= 0) atomicMaxFloat(&agg[th * 32 + c], acc);
    }
}

// ===== edge2: IC=32, OC=64, lane = out channel, A/B edge pair. R7 body.
__global__ void edge2_kernel(const float* __restrict__ xin, const int* __restrict__ src,
                             const int* __restrict__ tgt, const float* __restrict__ ea,
                             const int* __restrict__ order, int cap,
                             const float* __restrict__ U, const float* __restrict__ V,
                             float* __restrict__ agg) {
    int wid = (blockIdx.x * blockDim.x + threadIdx.x) >> 6;
    int lane = threadIdx.x & 63;
    int base = wid * CH2;
    if (base >= cap) return;
    int pk = order[base + (lane & (CH2 - 1))];
    int p0 = __builtin_amdgcn_readfirstlane(pk);
    if (p0 < 0) return;
    int seg = p0 >> 17;
    int ev = (pk < 0) ? 0 : (pk & PACK_MASK);
    int sv = src[ev], tv = tgt[ev];
    float av = ea[ev];
    float Ur[32], Vr[32];
    {
        const float* Us = U + seg * 2048 + lane;
        const float* Vs = V + seg * 2048 + lane;
#pragma unroll
        for (int i = 0; i < 32; ++i) { Ur[i] = Us[i * 64]; Vr[i] = Vs[i * 64]; }
    }
#pragma unroll
    for (int t = 0; t < CH2; t += 2) {
        int pA = __builtin_amdgcn_readlane(pk, t);
        int pB = __builtin_amdgcn_readlane(pk, t + 1);
        int sA = __builtin_amdgcn_readlane(sv, t);
        int sB = __builtin_amdgcn_readlane(sv, t + 1);
        int tA = __builtin_amdgcn_readlane(tv, t);
        int tB = __builtin_amdgcn_readlane(tv, t + 1);
        float aA = readlane_f(av, t);
        float aB = readlane_f(av, t + 1);
        const float* xA = xin + sA * 32;
        const float* xB = xin + sB * 32;
        float accA = 0.f, accB = 0.f;
#pragma unroll
        for (int i = 0; i < 32; ++i) {
            accA = fmaf(xA[i], fmaf(aA, Ur[i], Vr[i]), accA);
            accB = fmaf(xB[i], fmaf(aB, Ur[i], Vr[i]), accB);
        }
        if (pA >= 0) atomicMaxFloat(&agg[tA * 64 + lane], accA);
        if (pB >= 0) atomicMaxFloat(&agg[tB * 64 + lane], accB);
    }
}

// ===== node1: out = elu( fixup(agg) + x @ wr1 + bias1 ). R7 body.
__global__ void node1_kernel(const float* __restrict__ xin, const float* __restrict__ agg,
                             const float* __restrict__ wroot, const float* __restrict__ bias,
                             float* __restrict__ out, int N) {
    int idx = blockIdx.x * blockDim.x + threadIdx.x;
    if (idx >= N * 32) return;
    int n = idx >> 5, c = idx & 31;
    float v = agg[idx];
    if (v == -FLT_MAX) v = 0.f;
    float acc = v + bias[c];
#pragma unroll
    for (int i = 0; i < 16; ++i) acc = fmaf(xin[n * 16 + i], wroot[i * 32 + c], acc);
    out[idx] = acc > 0.f ? acc : expm1f(acc);
}

// ===== tail: node2 + fc1 + fc2 + log_softmax. R7 body: 4 nodes/wave, zero
// local arrays (allocator pins 64-VGPR budget; register arrays spill).
__global__ void tail_kernel(const float* __restrict__ h1, const float* __restrict__ agg2,
                            const float* __restrict__ wr2, const float* __restrict__ bias2,
                            const float* __restrict__ fc1w, const float* __restrict__ fc1b,
                            const float* __restrict__ fc2w, const float* __restrict__ fc2b,
                            float* __restrict__ out) {
    __shared__ __align__(16) float h1sh[4][TNB][32];
    __shared__ __align__(16) float h2sh[4][TNB][64];
    __shared__ __align__(16) float h3sh[4][TNB][132];   // +4 pad
    __shared__ __align__(16) float wTsh[10][132];       // fc2w transposed
    int tid = threadIdx.x;
    int wv = tid >> 6, lane = tid & 63;

    for (int t = tid; t < 1280; t += 256) {
        int k = t / 10, j = t - k * 10;
        wTsh[j][k] = fc2w[t];
    }
    __syncthreads();   // only barrier; everything below is wave-local

    int nb = blockIdx.x * (4 * TNB) + wv * TNB;

    {
        const float2* hp = (const float2*)(h1 + (size_t)nb * 32);
        ((float2*)&h1sh[wv][0][0])[lane] = hp[lane];
    }

    float b2v = bias2[lane];
    float ac0 = agg2[(size_t)(nb + 0) * 64 + lane];
    float ac1 = agg2[(size_t)(nb + 1) * 64 + lane];
    float ac2 = agg2[(size_t)(nb + 2) * 64 + lane];
    float ac3 = agg2[(size_t)(nb + 3) * 64 + lane];
    ac0 = (ac0 == -FLT_MAX ? 0.f : ac0) + b2v;
    ac1 = (ac1 == -FLT_MAX ? 0.f : ac1) + b2v;
    ac2 = (ac2 == -FLT_MAX ? 0.f : ac2) + b2v;
    ac3 = (ac3 == -FLT_MAX ? 0.f : ac3) + b2v;
#pragma unroll 8
    for (int i = 0; i < 32; ++i) {
        float w = wr2[i * 64 + lane];
        ac0 = fmaf(h1sh[wv][0][i], w, ac0);
        ac1 = fmaf(h1sh[wv][1][i], w, ac1);
        ac2 = fmaf(h1sh[wv][2][i], w, ac2);
        ac3 = fmaf(h1sh[wv][3][i], w, ac3);
    }
    h2sh[wv][0][lane] = elu_f(ac0);
    h2sh[wv][1][lane] = elu_f(ac1);
    h2sh[wv][2][lane] = elu_f(ac2);
    h2sh[wv][3][lane] = elu_f(ac3);

    float fb1 = fc1b[lane], fb2 = fc1b[64 + lane];
    float p0 = fb1, p1 = fb1, p2 = fb1, p3 = fb1;
    float q0 = fb2, q1 = fb2, q2 = fb2, q3 = fb2;
#pragma unroll 2
    for (int k4 = 0; k4 < 16; ++k4) {
        int k = k4 * 4;
        float wA0 = fc1w[(k + 0) * 128 + lane];
        float wB0 = fc1w[(k + 0) * 128 + 64 + lane];
        float wA1 = fc1w[(k + 1) * 128 + lane];
        float wB1 = fc1w[(k + 1) * 128 + 64 + lane];
        float wA2 = fc1w[(k + 2) * 128 + lane];
        float wB2 = fc1w[(k + 2) * 128 + 64 + lane];
        float wA3 = fc1w[(k + 3) * 128 + lane];
        float wB3 = fc1w[(k + 3) * 128 + 64 + lane];
        float4 g0 = ((const float4*)h2sh[wv][0])[k4];
        float4 g1 = ((const float4*)h2sh[wv][1])[k4];
        float4 g2 = ((const float4*)h2sh[wv][2])[k4];
        float4 g3 = ((const float4*)h2sh[wv][3])[k4];
        p0 = fmaf(g0.x, wA0, p0); p0 = fmaf(g0.y, wA1, p0);
        p0 = fmaf(g0.z, wA2, p0); p0 = fmaf(g0.w, wA3, p0);
        q0 = fmaf(g0.x, wB0, q0); q0 = fmaf(g0.y, wB1, q0);
        q0 = fmaf(g0.z, wB2, q0); q0 = fmaf(g0.w, wB3, q0);
        p1 = fmaf(g1.x, wA0, p1); p1 = fmaf(g1.y, wA1, p1);
        p1 = fmaf(g1.z, wA2, p1); p1 = fmaf(g1.w, wA3, p1);
        q1 = fmaf(g1.x, wB0, q1); q1 = fmaf(g1.y, wB1, q1);
        q1 = fmaf(g1.z, wB2, q1); q1 = fmaf(g1.w, wB3, q1);
        p2 = fmaf(g2.x, wA0, p2); p2 = fmaf(g2.y, wA1, p2);
        p2 = fmaf(g2.z, wA2, p2); p2 = fmaf(g2.w, wA3, p2);
        q2 = fmaf(g2.x, wB0, q2); q2 = fmaf(g2.y, wB1, q2);
        q2 = fmaf(g2.z, wB2, q2); q2 = fmaf(g2.w, wB3, q2);
        p3 = fmaf(g3.x, wA0, p3); p3 = fmaf(g3.y, wA1, p3);
        p3 = fmaf(g3.z, wA2, p3); p3 = fmaf(g3.w, wA3, p3);
        q3 = fmaf(g3.x, wB0, q3); q3 = fmaf(g3.y, wB1, q3);
        q3 = fmaf(g3.z, wB2, q3); q3 = fmaf(g3.w, wB3, q3);
    }
    h3sh[wv][0][lane] = elu_f(p0); h3sh[wv][0][64 + lane] = elu_f(q0);
    h3sh[wv][1][lane] = elu_f(p1); h3sh[wv][1][64 + lane] = elu_f(q1);
    h3sh[wv][2][lane] = elu_f(p2); h3sh[wv][2][64 + lane] = elu_f(q2);
    h3sh[wv][3][lane] = elu_f(p3); h3sh[wv][3][64 + lane] = elu_f(q3);

    {
        int n = lane >> 4, j = lane & 15;
        bool act = j < 10;
        int jc = act ? j : 0;
        float a = fc2b[jc];
        const float4* h3v = (const float4*)h3sh[wv][n];
        const float4* wv4 = (const float4*)wTsh[jc];
#pragma unroll
        for (int q = 0; q < 32; ++q) {
            float4 h = h3v[q];
            float4 w = wv4[q];
            a = fmaf(h.x, w.x, a);
            a = fmaf(h.y, w.y, a);
            a = fmaf(h.z, w.z, a);
            a = fmaf(h.w, w.w, a);
        }
        float lm = act ? a : -FLT_MAX;
        lm = fmaxf(lm, __shfl_xor(lm, 1, 16));
        lm = fmaxf(lm, __shfl_xor(lm, 2, 16));
        lm = fmaxf(lm, __shfl_xor(lm, 4, 16));
        lm = fmaxf(lm, __shfl_xor(lm, 8, 16));
        float ls = act ? expf(a - lm) : 0.f;
        ls += __shfl_xor(ls, 1, 16);
        ls += __shfl_xor(ls, 2, 16);
        ls += __shfl_xor(ls, 4, 16);
        ls += __shfl_xor(ls, 8, 16);
        if (act) out[(size_t)(nb + n) * 10 + j] = a - lm - logf(ls);
    }
}

extern "C" void kernel_launch(void* const* d_in, const int* in_sizes, int n_in,
                              void* d_out, int out_size, void* d_ws, size_t ws_size,
                              hipStream_t stream) {
    const float* x     = (const float*)d_in[0];
    const int*   eidx  = (const int*)d_in[1];
    const float* ea    = (const float*)d_in[2];
    const float* w1a   = (const float*)d_in[3];
    const float* b1a   = (const float*)d_in[4];
    const float* w1b   = (const float*)d_in[5];
    const float* b1b   = (const float*)d_in[6];
    const float* wr1   = (const float*)d_in[7];
    const float* bias1 = (const float*)d_in[8];
    const float* w2a   = (const float*)d_in[9];
    const float* b2a   = (const float*)d_in[10];
    const float* w2b   = (const float*)d_in[11];
    const float* b2b   = (const float*)d_in[12];
    const float* wr2   = (const float*)d_in[13];
    const float* bias2 = (const float*)d_in[14];
    const float* fc1w  = (const float*)d_in[15];
    const float* fc1b  = (const float*)d_in[16];
    const float* fc2w  = (const float*)d_in[17];
    const float* fc2b  = (const float*)d_in[18];

    const int N = in_sizes[0] / 16;   // 20000
    const int E = in_sizes[2];        // 100000
    const int* src = eidx;
    const int* tgt = eidx + E;

    const int cap1 = ((E + 26 * (CH1 - 1)) + CH1 - 1) / CH1 * CH1;
    const int cap2 = ((E + 26 * (CH2 - 1)) + CH2 - 1) / CH2 * CH2;

    float* ws = (float*)d_ws;
    size_t off = 0;
    int*   hist = (int*)(ws + off);   off += 64;   // hist+cur contiguous: 512B memset
    int*   cur  = (int*)(ws + off);   off += 64;
    int*   segp = (int*)(ws + off);   off += E;
    int*   ord1 = (int*)(ws + off);   off += cap1; // ord1/ord2 contiguous
    int*   ord2 = (int*)(ws + off);   off += cap2;
    float* U1   = ws + off;           off += 26 * 512;
    float* V1   = ws + off;           off += 26 * 512;
    float* U2   = ws + off;           off += 26 * 2048;
    float* V2   = ws + off;           off += 26 * 2048;
    float* AGG1 = ws + off;           off += (size_t)N * 32;  // AGG1/AGG2 contiguous
    float* AGG2 = ws + off;           off += (size_t)N * 64;
    float* H1b  = ws + off;           off += (size_t)N * 32;

    const int nAssign = (E + 255) / 256;   // 391

    PrepParams pp;
    pp.ea = ea; pp.w1a = w1a; pp.b1a = b1a; pp.w1b = w1b; pp.b1b = b1b;
    pp.w2a = w2a; pp.b2a = b2a; pp.w2b = w2b; pp.b2b = b2b;
    pp.hist = hist; pp.segp = segp; pp.ord1 = ord1;
    pp.U1 = U1; pp.V1 = V1; pp.U2 = U2; pp.V2 = V2; pp.AGG1 = AGG1;
    pp.N = N; pp.E = E; pp.capSum = cap1 + cap2;

    // 0. hist + cur = 0 (512 B; graph-capturable)
    hipMemsetAsync(hist, 0, 512, stream);
    // 1. fused fill + build_uv + assign_hist
    prep_kernel<<<K1_FILL + K1_UV + nAssign, 256, 0, stream>>>(pp);
    // 2. scatter with in-block scan (scanpad folded in)
    scatter_scan_kernel<<<nAssign, 256, 0, stream>>>(segp, E, hist, cur, ord1, ord2);
    // 3. conv1 edges
    {
        int waves = cap1 / CH1;
        edge1_kernel<<<(waves + 3) / 4, 256, 0, stream>>>(x, src, tgt, ea, ord1, cap1, U1, V1, AGG1);
    }
    // 4. conv1 node update
    node1_kernel<<<(N * 32 + 255) / 256, 256, 0, stream>>>(x, AGG1, wr1, bias1, H1b, N);
    // 5. conv2 edges
    {
        int waves = cap2 / CH2;
        edge2_kernel<<<(waves + 3) / 4, 256, 0, stream>>>(H1b, src, tgt, ea, ord2, cap2, U2, V2, AGG2);
    }
    // 6. fused node2 + fc1 + fc2 + log_softmax
    tail_kernel<<<N / 16, 256, 0, stream>>>(H1b, AGG2, wr2, bias2, fc1w, fc1b, fc2w, fc2b, (float*)d_out);
}